// Round 13
// baseline (113.612 us; speedup 1.0000x reference)
//
#include <hip/hip_runtime.h>
#include <stdint.h>

// Problem constants (LSHSoftmax): B=1024, D=512, N=500000, S=32768
#define B_DIM 1024
#define D_DIM 512
#define S_DIM 32768

typedef __attribute__((ext_vector_type(8))) short bf16x8;   // 8 bf16 = 4 VGPRs
typedef __attribute__((ext_vector_type(4))) float f32x4;
typedef __attribute__((ext_vector_type(8))) unsigned short u16x8;

#define AS1 __attribute__((address_space(1)))
#define AS3 __attribute__((address_space(3)))

__device__ __forceinline__ unsigned short f2bf(float f) {
  union { float f; uint32_t u; } x; x.f = f;
  uint32_t r = x.u + 0x7fffu + ((x.u >> 16) & 1u);   // RNE
  return (unsigned short)(r >> 16);
}
__device__ __forceinline__ uint32_t cvtpk(float a, float b) {
  uint32_t r;
  asm("v_cvt_pk_bf16_f32 %0, %1, %2" : "=v"(r) : "v"(a), "v"(b));
  return r;
}

// Convert inputs A f32 -> bf16 once (1 MiB; L2-resident for all GEMM blocks).
__global__ __launch_bounds__(256) void conv_a(const float* __restrict__ A,
                                              unsigned short* __restrict__ Ab) {
  int gid = blockIdx.x * 256 + threadIdx.x;
  const float* src = A + (size_t)gid * 8;
  float4 v0 = *(const float4*)src;
  float4 v1 = *(const float4*)(src + 4);
  u16x8 o;
  o[0] = f2bf(v0.x); o[1] = f2bf(v0.y); o[2] = f2bf(v0.z); o[3] = f2bf(v0.w);
  o[4] = f2bf(v1.x); o[5] = f2bf(v1.y); o[6] = f2bf(v1.z); o[7] = f2bf(v1.w);
  *(u16x8*)(Ab + (size_t)gid * 8) = o;
}

// ---------------------------------------------------------------------------
// r13 = r12 skeleton + software-pipelined fragments (LDS/MFMA overlap) +
// spread mid-kernel epilogues (vmcnt poison fix).
// 256 blocks (1/CU), block owns cols n0=b*128, rows as 4 mc-chunks of 256.
// Iter g (g = mc*16+kt, 64 iters): MFMA tile g using frags read at iter g-1;
// read frags(g+1); stage tile g+2. Two barriers/iter:
//   [vm-wait][BAR1: tile g+1 published][read frags(g+1)][lgkmcnt(8): frags(g)
//   retired][BAR2: all waves retired -> buf (g)&1 safe to re-stage]
//   [stage(g+2) -> buf g&1][spread-stores][MFMA(g) (no lgkm block)]
// Race proof: stage(g+2) overwrites buf g&1; its last reads (frags g) retired
// at every wave's lgkmcnt(8) before BAR2 of iter g; stage is after BAR2. ✓
// Publish proof: stage(g+1) loads (iter g-1) vm-waited by owner before BAR1
// of iter g; readers read after BAR1. ✓
// Store spreading: boundary b in {15,31,47}: acc->acc2, zero acc; iters
// b+1..b+8 emit 8 stores each AFTER the stage loads. In-order vmcnt:
// iters with (g&15)in[1,8],g>=17 use vmcnt(8) (2 stage loads are oldest
// unretired -> count<=8 proves them); others vmcnt(0) (queue = 2 loads only).
// LDS: A 2x16 KB @0 + B panel 128 KB @32768 = 160 KB. Swizzles = r12
// (verified): A pair-line XOR, B slot^(col&7).
// ---------------------------------------------------------------------------
#define BN 128
#define NG 64
#define B_OFF 32768

__global__ __launch_bounds__(512, 2) void gemm_fused(const unsigned short* __restrict__ Ab,
                                                     const float* __restrict__ W,
                                                     const float* __restrict__ bias,
                                                     const int* __restrict__ ids,
                                                     float* __restrict__ out) {
  __shared__ __attribute__((aligned(16))) char lds[163840];   // 160 KiB

  const int tid = threadIdx.x;
  const int lane = tid & 63;
  const int w = tid >> 6;            // wave 0..7
  const int wm = w >> 1;             // M-group 0..3 (64 rows of 256-chunk)
  const int wn = w & 1;              // N-group 0..1 (64 cols)
  const int lq = lane >> 4;          // 0..3
  const int l16 = lane & 15;
  const int n0 = blockIdx.x * BN;

  // A stage sources (r12 verbatim; inverse of read swizzle).
  const char* srcA[2];
#pragma unroll
  for (int j = 0; j < 2; ++j) {
    const int p = j * 512 + tid;
    const int line = p >> 3;
    const int sl = (p & 7) ^ (line & 7);
    const int row = line * 2 + (sl >> 2);
    srcA[j] = (const char*)Ab + row * 1024 + (sl & 3) * 16;
  }
  auto stage = [&](int g) {          // tile g: mc=g>>4 (256 rows), kt=g&15
    const int off = (g >> 4) * 262144 + (g & 15) * 64;
    char* dst = lds + (g & 1) * 16384 + w * 1024;
#pragma unroll
    for (int j = 0; j < 2; ++j)
      __builtin_amdgcn_global_load_lds((const AS1 void*)(srcA[j] + off),
                                       (AS3 void*)(dst + j * 8192), 16, 0, 0);
  };

  stage(0);                          // tile 0 loads under the gather

  // ---- Phase 1: gather + convert persistent B panel (r12 verbatim) ----
  {
    const int row = tid >> 2;
    const int c = tid & 3;
    const int myid = ids[n0 + row];
    const float* srcW = W + (size_t)myid * D_DIM;
    char* drow = lds + B_OFF + row * 1024;
    const int r7 = row & 7;
#pragma unroll
    for (int j = 0; j < 16; ++j) {
      const float* p = srcW + j * 32 + c * 8;
      float4 a = *(const float4*)p;
      float4 b = *(const float4*)(p + 4);
      int4 o;
      o.x = cvtpk(a.x, a.y); o.y = cvtpk(a.z, a.w);
      o.z = cvtpk(b.x, b.y); o.w = cvtpk(b.z, b.w);
      const int slot = (c + j * 4) ^ r7;
      *(int4*)(drow + slot * 16) = o;
    }
  }
  float bb[4];
#pragma unroll
  for (int n = 0; n < 4; ++n)
    bb[n] = bias[ids[n0 + wn * 64 + n * 16 + l16]];

  __syncthreads();                   // drains vmcnt+lgkmcnt: panel + tile0 ready

  // Fragment address pieces (r12 verbatim).
  int aoff[4];
#pragma unroll
  for (int m = 0; m < 4; ++m) {
    const int row = wm * 64 + m * 16 + l16;
    const int s = (((row & 1) << 2) | lq) ^ ((row >> 1) & 7);
    aoff[m] = (row >> 1) * 128 + s * 16;
  }
  int bbase[4], bx7[4];
#pragma unroll
  for (int n = 0; n < 4; ++n) {
    const int col = wn * 64 + n * 16 + l16;
    bbase[n] = B_OFF + col * 1024;
    bx7[n] = col & 7;
  }
  const int c0 = n0 + wn * 64 + l16;

  auto readf = [&](bf16x8 (&af)[4], bf16x8 (&bv)[4], int tile, int par) {
    const char* bufa = lds + par * 16384;
    const int kslot = (tile & 15) << 2;
#pragma unroll
    for (int m = 0; m < 4; ++m) af[m] = *(const bf16x8*)(bufa + aoff[m]);
#pragma unroll
    for (int n = 0; n < 4; ++n)
      bv[n] = *(const bf16x8*)(lds + bbase[n] + (((kslot + lq) ^ bx7[n]) << 4));
  };

  f32x4 acc[4][4], acc2[4][4];
#pragma unroll
  for (int m = 0; m < 4; ++m)
#pragma unroll
    for (int n = 0; n < 4; ++n) { acc[m][n] = (f32x4)0.0f; acc2[m][n] = (f32x4)0.0f; }

  bf16x8 afA[4], bvA[4], afB[4], bvB[4];

  stage(1);                          // 2 loads outstanding entering the loop
  readf(afA, bvA, 0, 0);             // frags(0) from buf0 (published by sync)

  int rt2 = wm * 64 + lq * 4;        // store row base for the acc2 snapshot

  // body(g, par=g&1, CUR, NXT): MFMA tile g; read frags g+1; stage g+2.
  auto body = [&](int g, int par, bf16x8 (&cAf)[4], bf16x8 (&cBv)[4],
                  bf16x8 (&nAf)[4], bf16x8 (&nBv)[4]) {
    const int gm = g & 15;
    const bool spread = (g >= 17) && (gm >= 1) && (gm <= 8);
    // vm-wait: confirm stage(g+1)'s 2 loads (oldest unretired VMEM).
    if (spread) asm volatile("s_waitcnt vmcnt(8)" ::: "memory");
    else        asm volatile("s_waitcnt vmcnt(0)" ::: "memory");
    __builtin_amdgcn_s_barrier();                    // BAR1: tile g+1 published
    __builtin_amdgcn_sched_barrier(0);
    if (g < NG - 1) readf(nAf, nBv, g + 1, par ^ 1); // 8 ds_reads, no wait
    __builtin_amdgcn_sched_barrier(0);
    asm volatile("s_waitcnt lgkmcnt(8)" ::: "memory"); // frags(g) retired
    __builtin_amdgcn_sched_barrier(0);
    __builtin_amdgcn_s_barrier();                    // BAR2: buf par free
    if (g < NG - 2) stage(g + 2);                    // into buf par
    __builtin_amdgcn_sched_barrier(0);
    // spread stores of the previous mc's snapshot (8/iter, after the loads).
    if (g >= 16 && gm <= 7) {
      const int jn = gm >> 1;                        // n index
      const int ms = (gm & 1) << 1;                  // m start (2 m's)
      const int cc = c0 + jn * 16;
      const int rb = ((g >> 4) - 1) * 256 + rt2;
#pragma unroll
      for (int t = 0; t < 2; ++t) {
        const int m = ms + t;
#pragma unroll
        for (int r = 0; r < 4; ++r)
          out[(size_t)(rb + m * 16 + r) * S_DIM + cc] = acc2[m][jn][r] + bb[jn];
      }
    }
    __builtin_amdgcn_sched_barrier(0);
    __builtin_amdgcn_s_setprio(1);
#pragma unroll
    for (int m = 0; m < 4; ++m)
#pragma unroll
      for (int n = 0; n < 4; ++n)
        acc[m][n] = __builtin_amdgcn_mfma_f32_16x16x32_bf16(cAf[m], cBv[n],
                                                            acc[m][n], 0, 0, 0);
    __builtin_amdgcn_s_setprio(0);
    __builtin_amdgcn_sched_barrier(0);
    if (gm == 15) {
      if (g == NG - 1) {
        // final epilogue: mc3, all 64 values, no waits after.
        const int rb = 3 * 256 + rt2;
#pragma unroll
        for (int n = 0; n < 4; ++n) {
          const int cc = c0 + n * 16;
#pragma unroll
          for (int m = 0; m < 4; ++m)
#pragma unroll
            for (int r = 0; r < 4; ++r)
              out[(size_t)(rb + m * 16 + r) * S_DIM + cc] = acc[m][n][r] + bb[n];
        }
      } else {
        // snapshot + reset for the next mc.
#pragma unroll
        for (int m = 0; m < 4; ++m)
#pragma unroll
          for (int n = 0; n < 4; ++n) {
            acc2[m][n] = acc[m][n];
            acc[m][n] = (f32x4)0.0f;
          }
      }
    }
  };

  for (int g = 0; g < NG; g += 2) {
    body(g,     0, afA, bvA, afB, bvB);
    body(g + 1, 1, afB, bvB, afA, bvA);
  }
}

extern "C" void kernel_launch(void* const* d_in, const int* in_sizes, int n_in,
                              void* d_out, int out_size, void* d_ws, size_t ws_size,
                              hipStream_t stream) {
  const float* inp  = (const float*)d_in[0];   // [B, D] f32
  const float* W    = (const float*)d_in[1];   // [N, D] f32
  const float* bias = (const float*)d_in[2];   // [N] f32
  const int*   ids  = (const int*)d_in[3];     // [S] int32
  float* out = (float*)d_out;                  // [B, S] f32

  unsigned short* Ab = (unsigned short*)d_ws;  // [B, D] bf16 (1 MiB)

  conv_a<<<(B_DIM * D_DIM / 8) / 256, 256, 0, stream>>>(inp, Ab);

  dim3 grid(S_DIM / BN);                       // 256 blocks = 1 per CU
  gemm_fused<<<grid, 512, 0, stream>>>(Ab, W, bias, ids, out);
}